// Round 1
// baseline (485.842 us; speedup 1.0000x reference)
//
#include <hip/hip_runtime.h>
#include <hip/hip_bf16.h>

#define TTOK 8192
#define DDIM 512
#define HDIM 2048
#define NEXP 8

typedef __bf16 bf16x8 __attribute__((ext_vector_type(8)));
typedef float f32x4 __attribute__((ext_vector_type(4)));

__device__ __forceinline__ unsigned short f2bf(float f) {
  unsigned int u = __builtin_bit_cast(unsigned int, f);
  u += 0x7fffu + ((u >> 16) & 1u);
  return (unsigned short)(u >> 16);
}

__device__ __forceinline__ void gll16(const void* g, void* l) {
  __builtin_amdgcn_global_load_lds(
      (__attribute__((address_space(1))) void*)g,
      (__attribute__((address_space(3))) void*)l, 16, 0, 0);
}

// ---------------- x fp32 -> bf16 ----------------
__global__ void k_cvt_x(const float* __restrict__ x, ushort4* __restrict__ xb) {
  int i = blockIdx.x * blockDim.x + threadIdx.x;
  const int n4 = TTOK * DDIM / 4;
  for (; i < n4; i += gridDim.x * blockDim.x) {
    float4 v = ((const float4*)x)[i];
    ushort4 o;
    o.x = f2bf(v.x); o.y = f2bf(v.y); o.z = f2bf(v.z); o.w = f2bf(v.w);
    xb[i] = o;
  }
}

// ---------------- per-expert [R][C] fp32 -> [C][R] bf16 ----------------
__global__ void k_transpose(const float* __restrict__ in, unsigned short* __restrict__ out,
                            int R, int C) {
  __shared__ float tile[32][33];
  const int e = blockIdx.z;
  const float* ine = in + (size_t)e * R * C;
  unsigned short* oute = out + (size_t)e * R * C;
  const int c0 = blockIdx.x * 32, r0 = blockIdx.y * 32;
  const int tx = threadIdx.x, ty = threadIdx.y;
#pragma unroll
  for (int i = 0; i < 32; i += 8)
    tile[ty + i][tx] = ine[(size_t)(r0 + ty + i) * C + (c0 + tx)];
  __syncthreads();
#pragma unroll
  for (int i = 0; i < 32; i += 8)
    oute[(size_t)(c0 + ty + i) * R + (r0 + tx)] = f2bf(tile[tx][ty + i]);
}

// ---------------- router: logits, top-2, gates, expert token lists ----------------
__global__ void k_router(const float* __restrict__ x, const float* __restrict__ rw,
                         const float* __restrict__ rb, float* __restrict__ logits,
                         int* __restrict__ counts, int* __restrict__ toklist,
                         float* __restrict__ gates) {
  const int t = blockIdx.x * 4 + (threadIdx.x >> 6);
  const int lane = threadIdx.x & 63;
  const float4* xr = (const float4*)(x + (size_t)t * DDIM);
  float4 v0 = xr[lane * 2], v1 = xr[lane * 2 + 1];
  float a[NEXP];
#pragma unroll
  for (int e = 0; e < NEXP; ++e) {
    const float4* wp = (const float4*)(rw + e * DDIM);
    float4 w0 = wp[lane * 2], w1v = wp[lane * 2 + 1];
    a[e] = v0.x * w0.x + v0.y * w0.y + v0.z * w0.z + v0.w * w0.w +
           v1.x * w1v.x + v1.y * w1v.y + v1.z * w1v.z + v1.w * w1v.w;
  }
#pragma unroll
  for (int off = 32; off > 0; off >>= 1)
#pragma unroll
    for (int e = 0; e < NEXP; ++e) a[e] += __shfl_xor(a[e], off, 64);

  if (lane == 0) {
    float lg[NEXP];
#pragma unroll
    for (int e = 0; e < NEXP; ++e) lg[e] = a[e] + rb[e];
    float4 s0, s1;
    s0.x = lg[0]; s0.y = lg[1]; s0.z = lg[2]; s0.w = lg[3];
    s1.x = lg[4]; s1.y = lg[5]; s1.z = lg[6]; s1.w = lg[7];
    ((float4*)(logits + t * NEXP))[0] = s0;
    ((float4*)(logits + t * NEXP))[1] = s1;
    int i0 = 0; float v0m = lg[0];
#pragma unroll
    for (int e = 1; e < NEXP; ++e) if (lg[e] > v0m) { v0m = lg[e]; i0 = e; }
    int i1 = (i0 == 0) ? 1 : 0; float v1m = -3.4e38f;
#pragma unroll
    for (int e = 0; e < NEXP; ++e) if (e != i0 && lg[e] > v1m) { v1m = lg[e]; i1 = e; }
    float e1 = expf(v1m - v0m);
    float inv = 1.0f / (1.0f + e1);
    int p0 = atomicAdd(&counts[i0], 1);
    toklist[i0 * TTOK + p0] = t; gates[i0 * TTOK + p0] = inv;
    int p1 = atomicAdd(&counts[i1], 1);
    toklist[i1 * TTOK + p1] = t; gates[i1 * TTOK + p1] = e1 * inv;
  }
}

// ---------------- tiny prefix sum for exact h packing ----------------
__global__ void k_offsets(const int* __restrict__ counts, int* __restrict__ offsets) {
  if (threadIdx.x == 0) {
    int s = 0;
    for (int e = 0; e < NEXP; ++e) { offsets[e] = s; s += counts[e]; }
  }
}

// ---------------- grouped GEMM; PHASE1: xb@w1 -> gelu -> h; PHASE2: h@w2 -> scatter out ----------------
template <int PHASE>
__global__ __launch_bounds__(256, 2) void k_gemm(
    const unsigned short* __restrict__ A, const unsigned short* __restrict__ Bt,
    const float* __restrict__ bias, const int* __restrict__ counts,
    const int* __restrict__ offsets, const int* __restrict__ toklist,
    const float* __restrict__ gates, unsigned short* __restrict__ Hout,
    float* __restrict__ Out) {
  constexpr int K = (PHASE == 1) ? DDIM : HDIM;   // reduction dim
  constexpr int NN = (PHASE == 1) ? HDIM : DDIM;  // output cols
  constexpr int KB = K * 2;                       // row bytes of A/Bt

  const int e = blockIdx.z;
  const int cnt = counts[e];
  const int m0 = blockIdx.y * 128;
  if (m0 >= cnt) return;
  const int n0 = blockIdx.x * 128;
  const int off = offsets[e];

  __shared__ alignas(16) unsigned char smem[32768];  // A tile 16KB | B tile 16KB

  const int tid = threadIdx.x;
  const int wid = tid >> 6, lane = tid & 63;

  // staging: 16 chunks of 1KB per tile; chunk c covers rows [c*8, c*8+8), 128B/row.
  // LDS dest stays linear (global_load_lds); source byte-in-row is pre-XOR-swizzled so
  // that the swizzled ds_read below sees the right data (both-sides involution).
  const char* asrc[4];
  const char* bsrc[4];
  unsigned adst[4], bdst[4];
#pragma unroll
  for (int i = 0; i < 4; ++i) {
    const int c = i * 4 + wid;
    const int r = c * 8 + (lane >> 3);
    const int cs = ((lane & 7) * 16) ^ ((r & 7) << 4);
    int mrow = m0 + r; if (mrow > cnt - 1) mrow = cnt - 1;
    if (PHASE == 1) {
      const int tok = toklist[(e << 13) + mrow];
      asrc[i] = (const char*)A + (size_t)tok * (DDIM * 2) + cs;
    } else {
      asrc[i] = (const char*)A + (size_t)(off + mrow) * KB + cs;
    }
    bsrc[i] = (const char*)Bt + (size_t)e * NN * KB + (size_t)(n0 + r) * KB + cs;
    adst[i] = c * 1024;
    bdst[i] = 16384 + c * 1024;
  }

  f32x4 acc[4][4] = {};

  const int wr = wid >> 1, wc = wid & 1;
  const int lr = lane & 15, lk = lane >> 4;

  for (int k0 = 0; k0 < K; k0 += 64) {
#pragma unroll
    for (int i = 0; i < 4; ++i) gll16(asrc[i] + k0 * 2, smem + adst[i]);
#pragma unroll
    for (int i = 0; i < 4; ++i) gll16(bsrc[i] + k0 * 2, smem + bdst[i]);
    __syncthreads();
#pragma unroll
    for (int kk = 0; kk < 2; ++kk) {
      bf16x8 af[4], bv[4];
#pragma unroll
      for (int mi = 0; mi < 4; ++mi) {
        const int r = wr * 64 + mi * 16 + lr;
        const int byteo = r * 128 + ((kk * 64 + lk * 16) ^ ((r & 7) << 4));
        af[mi] = *(const bf16x8*)(smem + byteo);
      }
#pragma unroll
      for (int ni = 0; ni < 4; ++ni) {
        const int r = wc * 64 + ni * 16 + lr;
        const int byteo = 16384 + r * 128 + ((kk * 64 + lk * 16) ^ ((r & 7) << 4));
        bv[ni] = *(const bf16x8*)(smem + byteo);
      }
#pragma unroll
      for (int mi = 0; mi < 4; ++mi)
#pragma unroll
        for (int ni = 0; ni < 4; ++ni)
          acc[mi][ni] = __builtin_amdgcn_mfma_f32_16x16x32_bf16(af[mi], bv[ni], acc[mi][ni], 0, 0, 0);
    }
    __syncthreads();
  }

  // epilogue: C/D layout col = lane&15, row = (lane>>4)*4 + reg
  const int lq = lane >> 4;
  if (PHASE == 1) {
#pragma unroll
    for (int mi = 0; mi < 4; ++mi) {
#pragma unroll
      for (int ni = 0; ni < 4; ++ni) {
        const int n = n0 + wc * 64 + ni * 16 + lr;
        const float bv_ = bias[e * NN + n];
#pragma unroll
        for (int r2 = 0; r2 < 4; ++r2) {
          const int m = m0 + wr * 64 + mi * 16 + lq * 4 + r2;
          if (m < cnt) {
            const float xv = acc[mi][ni][r2] + bv_;
            const float g = 0.5f * xv * (1.0f + erff(xv * 0.70710678118f));
            Hout[(size_t)(off + m) * HDIM + n] = f2bf(g);
          }
        }
      }
    }
  } else {
#pragma unroll
    for (int mi = 0; mi < 4; ++mi) {
#pragma unroll
      for (int r2 = 0; r2 < 4; ++r2) {
        const int m = m0 + wr * 64 + mi * 16 + lq * 4 + r2;
        if (m < cnt) {
          const int tok = toklist[(e << 13) + m];
          const float g = gates[(e << 13) + m];
#pragma unroll
          for (int ni = 0; ni < 4; ++ni) {
            const int n = n0 + wc * 64 + ni * 16 + lr;
            const float y = acc[mi][ni][r2] + bias[e * NN + n];
            atomicAdd(Out + (size_t)tok * DDIM + n, g * y);
          }
        }
      }
    }
  }
}

extern "C" void kernel_launch(void* const* d_in, const int* in_sizes, int n_in,
                              void* d_out, int out_size, void* d_ws, size_t ws_size,
                              hipStream_t stream) {
  (void)in_sizes; (void)n_in; (void)out_size; (void)ws_size;
  const float* x  = (const float*)d_in[0];
  const float* rw = (const float*)d_in[1];
  const float* rb = (const float*)d_in[2];
  const float* w1 = (const float*)d_in[3];
  const float* b1 = (const float*)d_in[4];
  const float* w2 = (const float*)d_in[5];
  const float* b2 = (const float*)d_in[6];
  float* out = (float*)d_out;
  float* logits = out + (size_t)TTOK * DDIM;

  char* ws = (char*)d_ws;
  // workspace layout (bytes), total ~104.6 MB
  unsigned short* xb  = (unsigned short*)(ws + 0);          //  8,388,608
  unsigned short* w1t = (unsigned short*)(ws + 8388608);    // 16,777,216  [E][H][D] bf16
  unsigned short* w2t = (unsigned short*)(ws + 25165824);   // 16,777,216  [E][D][H] bf16
  unsigned short* h   = (unsigned short*)(ws + 41943040);   // 67,108,864  [16384][H] bf16
  int*   toklist = (int*)(ws + 109051904);                  //    262,144
  float* gates   = (float*)(ws + 109314048);                //    262,144
  int*   counts  = (int*)(ws + 109576192);                  //         32
  int*   offsets = (int*)(ws + 109576224);                  //         32

  hipMemsetAsync(out, 0, (size_t)TTOK * DDIM * sizeof(float), stream);
  hipMemsetAsync(counts, 0, 64, stream);

  k_cvt_x<<<2048, 256, 0, stream>>>(x, (ushort4*)xb);
  k_transpose<<<dim3(HDIM / 32, DDIM / 32, NEXP), dim3(32, 8), 0, stream>>>(w1, w1t, DDIM, HDIM);
  k_transpose<<<dim3(DDIM / 32, HDIM / 32, NEXP), dim3(32, 8), 0, stream>>>(w2, w2t, HDIM, DDIM);
  k_router<<<TTOK / 4, 256, 0, stream>>>(x, rw, rb, logits, counts, toklist, gates);
  k_offsets<<<1, 64, 0, stream>>>(counts, offsets);

  k_gemm<1><<<dim3(HDIM / 128, TTOK / 128, NEXP), 256, 0, stream>>>(
      xb, w1t, b1, counts, offsets, toklist, gates, h, nullptr);
  k_gemm<2><<<dim3(DDIM / 128, TTOK / 128, NEXP), 256, 0, stream>>>(
      h, w2t, b2, counts, offsets, toklist, gates, nullptr, out);
}

// Round 3
// 320.900 us; speedup vs baseline: 1.5140x; 1.5140x over previous
//
#include <hip/hip_runtime.h>
#include <hip/hip_bf16.h>

#define TTOK 8192
#define DDIM 512
#define HDIM 2048
#define NEXP 8
#define RBLK 256                 // router blocks
#define RTOK (TTOK / RBLK)       // 32 tokens per router block

typedef __bf16 bf16x8 __attribute__((ext_vector_type(8)));
typedef float f32x4 __attribute__((ext_vector_type(4)));
typedef unsigned short us8 __attribute__((ext_vector_type(8)));

__device__ __forceinline__ unsigned short f2bf(float f) {
  unsigned int u = __builtin_bit_cast(unsigned int, f);
  u += 0x7fffu + ((u >> 16) & 1u);
  return (unsigned short)(u >> 16);
}

__device__ __forceinline__ void gll16(const void* g, void* l) {
  __builtin_amdgcn_global_load_lds(
      (__attribute__((address_space(1))) void*)g,
      (__attribute__((address_space(3))) void*)l, 16, 0, 0);
}

// ---------------- router: logits, top-2, gates, per-block positions; fused x->bf16 ----------------
__global__ __launch_bounds__(256) void k_router(
    const float* __restrict__ x, const float* __restrict__ rw,
    const float* __restrict__ rb, float* __restrict__ logits,
    unsigned short* __restrict__ xb,
    short* __restrict__ texp, unsigned short* __restrict__ tpos,
    float* __restrict__ tgate, int* __restrict__ blockcnt) {
  __shared__ int lcnt[NEXP];
  const int tid = threadIdx.x, wid = tid >> 6, lane = tid & 63;
  if (tid < NEXP) lcnt[tid] = 0;
  __syncthreads();
  // hoist router weights: lane covers floats [lane*8, lane*8+8)
  float4 w0[NEXP], w1[NEXP];
  float rbv[NEXP];
#pragma unroll
  for (int e = 0; e < NEXP; ++e) {
    const float4* wp = (const float4*)(rw + e * DDIM);
    w0[e] = wp[lane * 2];
    w1[e] = wp[lane * 2 + 1];
    rbv[e] = rb[e];
  }
  const int tbase = blockIdx.x * RTOK;
  for (int it = 0; it < RTOK / 4; ++it) {
    const int t = tbase + it * 4 + wid;
    const float4* xr = (const float4*)(x + (size_t)t * DDIM);
    float4 v0 = xr[lane * 2], v1 = xr[lane * 2 + 1];
    // fused bf16 conversion (replaces a separate k_cvt_x pass)
    us8 o;
    o[0] = f2bf(v0.x); o[1] = f2bf(v0.y); o[2] = f2bf(v0.z); o[3] = f2bf(v0.w);
    o[4] = f2bf(v1.x); o[5] = f2bf(v1.y); o[6] = f2bf(v1.z); o[7] = f2bf(v1.w);
    *(us8*)(xb + (size_t)t * DDIM + lane * 8) = o;
    float a[NEXP];
#pragma unroll
    for (int e = 0; e < NEXP; ++e)
      a[e] = v0.x * w0[e].x + v0.y * w0[e].y + v0.z * w0[e].z + v0.w * w0[e].w +
             v1.x * w1[e].x + v1.y * w1[e].y + v1.z * w1[e].z + v1.w * w1[e].w;
#pragma unroll
    for (int off = 32; off > 0; off >>= 1)
#pragma unroll
      for (int e = 0; e < NEXP; ++e) a[e] += __shfl_xor(a[e], off, 64);
    if (lane == 0) {
      float lg[NEXP];
#pragma unroll
      for (int e = 0; e < NEXP; ++e) lg[e] = a[e] + rbv[e];
      float4 s0, s1;
      s0.x = lg[0]; s0.y = lg[1]; s0.z = lg[2]; s0.w = lg[3];
      s1.x = lg[4]; s1.y = lg[5]; s1.z = lg[6]; s1.w = lg[7];
      ((float4*)(logits + t * NEXP))[0] = s0;
      ((float4*)(logits + t * NEXP))[1] = s1;
      int i0 = 0; float m0 = lg[0];
#pragma unroll
      for (int e = 1; e < NEXP; ++e) if (lg[e] > m0) { m0 = lg[e]; i0 = e; }
      int i1 = 0; float m1 = -3.4e38f;
#pragma unroll
      for (int e = 0; e < NEXP; ++e) if (e != i0 && lg[e] > m1) { m1 = lg[e]; i1 = e; }
      float e1 = expf(m1 - m0);
      float inv = 1.0f / (1.0f + e1);
      int p0 = atomicAdd(&lcnt[i0], 1);  // LDS atomic: block-local, cheap
      int p1 = atomicAdd(&lcnt[i1], 1);
      texp[t * 2] = (short)i0;     tpos[t * 2] = (unsigned short)p0;     tgate[t * 2] = inv;
      texp[t * 2 + 1] = (short)i1; tpos[t * 2 + 1] = (unsigned short)p1; tgate[t * 2 + 1] = e1 * inv;
    }
  }
  __syncthreads();
  if (tid < NEXP) blockcnt[blockIdx.x * NEXP + tid] = lcnt[tid];
}

// ---------------- per-block bases + expert counts/offsets (one wave) ----------------
__global__ void k_offsets(const int* __restrict__ blockcnt, int* __restrict__ blockbase,
                          int* __restrict__ counts, int* __restrict__ offsets) {
  const int e = threadIdx.x;
  if (e < NEXP) {
    int run = 0;
#pragma unroll 8
    for (int b = 0; b < RBLK; ++b) {
      blockbase[b * NEXP + e] = run;
      run += blockcnt[b * NEXP + e];
    }
    counts[e] = run;
  }
  __syncthreads();
  if (e == 0) {
    int s = 0;
    for (int q = 0; q < NEXP; ++q) { offsets[q] = s; s += counts[q]; }
  }
}

// ---------------- scatter: build packed per-expert token lists ----------------
// NOTE: toklist/gates are per-expert segments (stride TTOK), so the position is
// blockbase+tpos ONLY. offsets[e] is used exclusively for the packed-h layout
// inside k_gemm. (Round-2 bug: adding offsets[e] here double-counted and wrote
// past toklist -> poisoned reads -> wild global_load_lds -> GPU fault.)
__global__ void k_scatter(const short* __restrict__ texp, const unsigned short* __restrict__ tpos,
                          const float* __restrict__ tgate, const int* __restrict__ blockbase,
                          int* __restrict__ toklist, float* __restrict__ gates) {
  const int t = blockIdx.x * 256 + threadIdx.x;
  const int b = t / RTOK;
#pragma unroll
  for (int k = 0; k < 2; ++k) {
    const int e = (int)texp[t * 2 + k];
    const int pos = blockbase[b * NEXP + e] + (int)tpos[t * 2 + k];
    toklist[e * TTOK + pos] = t;
    gates[e * TTOK + pos] = tgate[t * 2 + k];
  }
}

// ---------------- per-expert [R][C] fp32 -> [C][R] bf16 ----------------
__global__ void k_transpose(const float* __restrict__ in, unsigned short* __restrict__ out,
                            int R, int C) {
  __shared__ float tile[32][33];
  const int e = blockIdx.z;
  const float* ine = in + (size_t)e * R * C;
  unsigned short* oute = out + (size_t)e * R * C;
  const int c0 = blockIdx.x * 32, r0 = blockIdx.y * 32;
  const int tx = threadIdx.x, ty = threadIdx.y;
#pragma unroll
  for (int i = 0; i < 32; i += 8)
    tile[ty + i][tx] = ine[(size_t)(r0 + ty + i) * C + (c0 + tx)];
  __syncthreads();
#pragma unroll
  for (int i = 0; i < 32; i += 8)
    oute[(size_t)(c0 + ty + i) * R + (r0 + tx)] = f2bf(tile[tx][ty + i]);
}

// ---------------- grouped GEMM; PHASE1: xb@w1 -> gelu -> h; PHASE2: h@w2 -> scatter out ----------------
template <int PHASE>
__global__ __launch_bounds__(256, 2) void k_gemm(
    const unsigned short* __restrict__ A, const unsigned short* __restrict__ Bt,
    const float* __restrict__ bias, const int* __restrict__ counts,
    const int* __restrict__ offsets, const int* __restrict__ toklist,
    const float* __restrict__ gates, unsigned short* __restrict__ Hout,
    float* __restrict__ Out) {
  constexpr int K = (PHASE == 1) ? DDIM : HDIM;   // reduction dim
  constexpr int NN = (PHASE == 1) ? HDIM : DDIM;  // output cols
  constexpr int KB = K * 2;                       // row bytes of A/Bt

  const int e = blockIdx.z;
  const int cnt = counts[e];
  const int m0 = blockIdx.y * 128;
  if (m0 >= cnt) return;
  const int n0 = blockIdx.x * 128;
  const int off = offsets[e];

  __shared__ alignas(16) unsigned char smem[32768];  // A tile 16KB | B tile 16KB

  const int tid = threadIdx.x;
  const int wid = tid >> 6, lane = tid & 63;

  // staging: 16 chunks of 1KB per tile; chunk c covers rows [c*8, c*8+8), 128B/row.
  // LDS dest stays linear (global_load_lds); source byte-in-row is pre-XOR-swizzled so
  // that the swizzled ds_read below sees the right data (both-sides involution).
  const char* asrc[4];
  const char* bsrc[4];
  unsigned adst[4], bdst[4];
#pragma unroll
  for (int i = 0; i < 4; ++i) {
    const int c = i * 4 + wid;
    const int r = c * 8 + (lane >> 3);
    const int cs = ((lane & 7) * 16) ^ ((r & 7) << 4);
    int mrow = m0 + r; if (mrow > cnt - 1) mrow = cnt - 1;
    if (PHASE == 1) {
      const int tok = toklist[(e << 13) + mrow];
      asrc[i] = (const char*)A + (size_t)tok * (DDIM * 2) + cs;
    } else {
      asrc[i] = (const char*)A + (size_t)(off + mrow) * KB + cs;
    }
    bsrc[i] = (const char*)Bt + (size_t)e * NN * KB + (size_t)(n0 + r) * KB + cs;
    adst[i] = c * 1024;
    bdst[i] = 16384 + c * 1024;
  }

  f32x4 acc[4][4] = {};

  const int wr = wid >> 1, wc = wid & 1;
  const int lr = lane & 15, lk = lane >> 4;

  for (int k0 = 0; k0 < K; k0 += 64) {
#pragma unroll
    for (int i = 0; i < 4; ++i) gll16(asrc[i] + k0 * 2, smem + adst[i]);
#pragma unroll
    for (int i = 0; i < 4; ++i) gll16(bsrc[i] + k0 * 2, smem + bdst[i]);
    __syncthreads();
#pragma unroll
    for (int kk = 0; kk < 2; ++kk) {
      bf16x8 af[4], bv[4];
#pragma unroll
      for (int mi = 0; mi < 4; ++mi) {
        const int r = wr * 64 + mi * 16 + lr;
        const int byteo = r * 128 + ((kk * 64 + lk * 16) ^ ((r & 7) << 4));
        af[mi] = *(const bf16x8*)(smem + byteo);
      }
#pragma unroll
      for (int ni = 0; ni < 4; ++ni) {
        const int r = wc * 64 + ni * 16 + lr;
        const int byteo = 16384 + r * 128 + ((kk * 64 + lk * 16) ^ ((r & 7) << 4));
        bv[ni] = *(const bf16x8*)(smem + byteo);
      }
#pragma unroll
      for (int mi = 0; mi < 4; ++mi)
#pragma unroll
        for (int ni = 0; ni < 4; ++ni)
          acc[mi][ni] = __builtin_amdgcn_mfma_f32_16x16x32_bf16(af[mi], bv[ni], acc[mi][ni], 0, 0, 0);
    }
    __syncthreads();
  }

  // epilogue: C/D layout col = lane&15, row = (lane>>4)*4 + reg
  const int lq = lane >> 4;
  if (PHASE == 1) {
#pragma unroll
    for (int mi = 0; mi < 4; ++mi) {
#pragma unroll
      for (int ni = 0; ni < 4; ++ni) {
        const int n = n0 + wc * 64 + ni * 16 + lr;
        const float bv_ = bias[e * NN + n];
#pragma unroll
        for (int r2 = 0; r2 < 4; ++r2) {
          const int m = m0 + wr * 64 + mi * 16 + lq * 4 + r2;
          if (m < cnt) {
            const float xv = acc[mi][ni][r2] + bv_;
            const float g = 0.5f * xv * (1.0f + erff(xv * 0.70710678118f));
            Hout[(size_t)(off + m) * HDIM + n] = f2bf(g);
          }
        }
      }
    }
  } else {
#pragma unroll
    for (int mi = 0; mi < 4; ++mi) {
#pragma unroll
      for (int r2 = 0; r2 < 4; ++r2) {
        const int m = m0 + wr * 64 + mi * 16 + lq * 4 + r2;
        if (m < cnt) {
          const int tok = toklist[(e << 13) + m];
          const float g = gates[(e << 13) + m];
#pragma unroll
          for (int ni = 0; ni < 4; ++ni) {
            const int n = n0 + wc * 64 + ni * 16 + lr;
            const float y = acc[mi][ni][r2] + bias[e * NN + n];
            atomicAdd(Out + (size_t)tok * DDIM + n, g * y);
          }
        }
      }
    }
  }
}

extern "C" void kernel_launch(void* const* d_in, const int* in_sizes, int n_in,
                              void* d_out, int out_size, void* d_ws, size_t ws_size,
                              hipStream_t stream) {
  (void)in_sizes; (void)n_in; (void)out_size; (void)ws_size;
  const float* x  = (const float*)d_in[0];
  const float* rw = (const float*)d_in[1];
  const float* rb = (const float*)d_in[2];
  const float* w1 = (const float*)d_in[3];
  const float* b1 = (const float*)d_in[4];
  const float* w2 = (const float*)d_in[5];
  const float* b2 = (const float*)d_in[6];
  float* out = (float*)d_out;
  float* logits = out + (size_t)TTOK * DDIM;

  char* ws = (char*)d_ws;
  // workspace layout (bytes), total ~109.6 MB
  unsigned short* xb  = (unsigned short*)(ws + 0);          //  8,388,608
  unsigned short* w1t = (unsigned short*)(ws + 8388608);    // 16,777,216  [E][H][D] bf16
  unsigned short* w2t = (unsigned short*)(ws + 25165824);   // 16,777,216  [E][D][H] bf16
  unsigned short* h   = (unsigned short*)(ws + 41943040);   // 67,108,864  [16384][H] bf16
  int*   toklist = (int*)(ws + 109051904);                  //    262,144
  float* gates   = (float*)(ws + 109314048);                //    262,144
  int*   counts  = (int*)(ws + 109576192);                  //         32
  int*   offsets = (int*)(ws + 109576224);                  //         32
  // router scratch ALIASED into the h region: consumed by k_scatter strictly
  // before k_gemm<1> writes h (stream-ordered), so no extra footprint.
  char* rsc = ws + 41943040;
  short*          texp      = (short*)(rsc + 0);            //  32,768
  unsigned short* tpos      = (unsigned short*)(rsc + 32768); // 32,768
  float*          tgate     = (float*)(rsc + 65536);        //  65,536
  int*            blockcnt  = (int*)(rsc + 131072);         //   8,192
  int*            blockbase = (int*)(rsc + 139264);         //   8,192

  hipMemsetAsync(out, 0, (size_t)TTOK * DDIM * sizeof(float), stream);

  k_router<<<RBLK, 256, 0, stream>>>(x, rw, rb, logits, xb, texp, tpos, tgate, blockcnt);
  k_transpose<<<dim3(HDIM / 32, DDIM / 32, NEXP), dim3(32, 8), 0, stream>>>(w1, w1t, DDIM, HDIM);
  k_transpose<<<dim3(DDIM / 32, HDIM / 32, NEXP), dim3(32, 8), 0, stream>>>(w2, w2t, HDIM, DDIM);
  k_offsets<<<1, 64, 0, stream>>>(blockcnt, blockbase, counts, offsets);
  k_scatter<<<TTOK / 256, 256, 0, stream>>>(texp, tpos, tgate, blockbase, toklist, gates);

  k_gemm<1><<<dim3(HDIM / 128, TTOK / 128, NEXP), 256, 0, stream>>>(
      xb, w1t, b1, counts, offsets, toklist, gates, h, nullptr);
  k_gemm<2><<<dim3(DDIM / 128, TTOK / 128, NEXP), 256, 0, stream>>>(
      h, w2t, b2, counts, offsets, toklist, gates, nullptr, out);
}